// Round 4
// baseline (25.482 us; speedup 1.0000x reference)
//
#include <hip/hip_runtime.h>
#include <math.h>

namespace {
constexpr int   KMAX   = 12;
constexpr int   NLINE  = 313;                    // half-space (h,k) lines
constexpr int   NL25   = 25;                     // l = -12..12 per line
constexpr int   NKV    = NLINE * NL25;           // 7825 (13 masked in stage2)
constexpr int   NSLICE = 8;                      // particle slices
constexpr int   SLICE_CAP = 512;                 // staged particles per chunk
constexpr int   S2_BLOCKS = (NKV + 255) / 256;   // 31
constexpr float ALPHA_  = 0.34f;
constexpr float TWO_PI_ = 6.283185307179586f;
}

__device__ __forceinline__ void cofactors(const float* __restrict__ box,
                                          float C[3][3], float* det) {
  const float b00 = box[0], b01 = box[1], b02 = box[2];
  const float b10 = box[3], b11 = box[4], b12 = box[5];
  const float b20 = box[6], b21 = box[7], b22 = box[8];
  C[0][0] =  (b11 * b22 - b12 * b21);
  C[0][1] = -(b10 * b22 - b12 * b20);
  C[0][2] =  (b10 * b21 - b11 * b20);
  C[1][0] = -(b01 * b22 - b02 * b21);
  C[1][1] =  (b00 * b22 - b02 * b20);
  C[1][2] = -(b00 * b21 - b01 * b20);
  C[2][0] =  (b01 * b12 - b02 * b11);
  C[2][1] = -(b00 * b12 - b02 * b10);
  C[2][2] =  (b00 * b11 - b01 * b10);
  *det = b00 * C[0][0] + b01 * C[0][1] + b02 * C[0][2];
}

// Half-space lines: L<300: h=1..12 x k=-12..12; L=300..311: h=0,k=1..12; L=312: h=k=0.
__device__ __forceinline__ void line_hk(int L, int* h, int* k) {
  if (L < 300)      { *h = L / 25 + 1; *k = L % 25 - 12; }
  else if (L < 312) { *h = 0;          *k = L - 299;     }
  else              { *h = 0;          *k = 0;           }
}

// One wave = one (h,k) line (all 25 l via center-out rotation chains) x one slice.
// Per (particle, line): 1 fract + 2 trans; rotator e^{2*pi*i*c} staged in LDS.
__global__ __launch_bounds__(256) void ewald_lines(
    const float* __restrict__ coords, const float* __restrict__ box,
    const float* __restrict__ q, int N, float* __restrict__ partial)
{
  __shared__ float4 sf[SLICE_CAP];   // (a, b, cr, sr)
  __shared__ float  sq[SLICE_CAP];   // q

  float C[3][3], det;
  cofactors(box, C, &det);
  const float invdet = 1.0f / det;

  const int slice = blockIdx.y;
  const int sp    = (N + NSLICE - 1) / NSLICE;
  const int s_beg = slice * sp;
  const int s_end = min(s_beg + sp, N);

  const int lane = threadIdx.x & 63;
  const int gl   = blockIdx.x * 4 + (threadIdx.x >> 6);   // unclamped line id
  const int line = (gl < NLINE) ? gl : (NLINE - 1);
  int h, k; line_hk(line, &h, &k);
  const float hf = (float)h, kf = (float)k;

  float Sre[NL25], Sim[NL25];
#pragma unroll
  for (int u = 0; u < NL25; ++u) { Sre[u] = 0.f; Sim[u] = 0.f; }

  for (int cb = s_beg; cb < s_end; cb += SLICE_CAP) {
    const int cnt = min(SLICE_CAP, s_end - cb);
    __syncthreads();
    for (int t = threadIdx.x; t < SLICE_CAP; t += 256) {
      float4 v = make_float4(0.f, 0.f, 1.f, 0.f);
      float qq = 0.f;
      if (t < cnt) {
        const int gi = cb + t;
        const float x = coords[3 * gi + 0];
        const float y = coords[3 * gi + 1];
        const float z = coords[3 * gi + 2];
        v.x = (x * C[0][0] + y * C[0][1] + z * C[0][2]) * invdet;    // a
        v.y = (x * C[1][0] + y * C[1][1] + z * C[1][2]) * invdet;    // b
        float c = (x * C[2][0] + y * C[2][1] + z * C[2][2]) * invdet;
        c = c - floorf(c);
        float cr, sr;
        asm("v_sin_f32 %0, %1" : "=v"(sr) : "v"(c));
        asm("v_cos_f32 %0, %1" : "=v"(cr) : "v"(c));
        v.z = cr; v.w = sr;
        qq = q[gi];
      }
      sf[t] = v; sq[t] = qq;
    }
    __syncthreads();

    for (int i = lane; i < SLICE_CAP; i += 64) {
      const float4 p = sf[i];
      const float qq = sq[i];
      float t00 = fmaf(hf, p.x, kf * p.y);   // phase at l=0, in revolutions
      float tf;
      asm("v_fract_f32 %0, %1" : "=v"(tf) : "v"(t00));
      float s0, c0;
      asm("v_sin_f32 %0, %1" : "=v"(s0) : "v"(tf));
      asm("v_cos_f32 %0, %1" : "=v"(c0) : "v"(tf));
      float Pur = qq * c0, Pui = qq * s0;    // l=0 phasor (q folded in)
      float Pdr = Pur,     Pdi = Pui;
      Sre[12] += Pur; Sim[12] += Pui;
      const float cr = p.z, sr = p.w;
#pragma unroll
      for (int u = 1; u <= 12; ++u) {
        // up chain: P *= (cr + i*sr)
        const float nur = fmaf(Pur, cr, -(Pui * sr));
        const float nui = fmaf(Pur, sr,  (Pui * cr));
        Pur = nur; Pui = nui;
        Sre[12 + u] += Pur; Sim[12 + u] += Pui;
        // down chain: P *= (cr - i*sr)
        const float ndr = fmaf(Pdr, cr,  (Pdi * sr));
        const float ndi = fmaf(Pdi, cr, -(Pdr * sr));
        Pdr = ndr; Pdi = ndi;
        Sre[12 - u] += Pdr; Sim[12 - u] += Pdi;
      }
    }
  }

  // 3-step butterfly: every lane ends holding the sum of its mod-8 lane group.
#pragma unroll
  for (int off = 32; off >= 8; off >>= 1) {
#pragma unroll
    for (int u = 0; u < NL25; ++u) {
      Sre[u] += __shfl_xor(Sre[u], off);
      Sim[u] += __shfl_xor(Sim[u], off);
    }
  }

  if (gl < NLINE && lane < 8) {
    float2* dst = (float2*)partial;
#pragma unroll
    for (int u = 0; u < NL25; ++u) {
      const size_t idx = ((size_t)(line * NL25 + u) * NSLICE + slice) * 8 + lane;
      dst[idx] = make_float2(Sre[u], Sim[u]);
    }
  }
}

// Sum the 64 partials per k, square, weight by fac; per-block sums (deterministic).
__global__ __launch_bounds__(256) void stage2(
    const float* __restrict__ partial, const float* __restrict__ box,
    float* __restrict__ bsum)
{
  __shared__ float red[256];
  const int idx = blockIdx.x * 256 + threadIdx.x;
  float e = 0.f;
  if (idx < NKV) {
    const int line = idx / NL25;
    const int l    = idx % NL25 - KMAX;
    int h, k; line_hk(line, &h, &k);
    if (!(h == 0 && k == 0 && l <= 0)) {   // mask the 13 non-half-space entries
      const float2* p = (const float2*)partial + (size_t)idx * (NSLICE * 8);
      float re = 0.f, im = 0.f;
      for (int j = 0; j < NSLICE * 8; ++j) { re += p[j].x; im += p[j].y; }
      float C[3][3], det;
      cofactors(box, C, &det);
      const float invdet = 1.0f / det;
      const float hf = (float)h, kf = (float)k, lf = (float)l;
      const float kx = (hf * C[0][0] + kf * C[1][0] + lf * C[2][0]) * invdet;
      const float ky = (hf * C[0][1] + kf * C[1][1] + lf * C[2][1]) * invdet;
      const float kz = (hf * C[0][2] + kf * C[1][2] + lf * C[2][2]) * invdet;
      const float k2 = TWO_PI_ * TWO_PI_ * (kx * kx + ky * ky + kz * kz);
      const float fac = __expf(-k2 / (4.0f * ALPHA_ * ALPHA_)) / k2;
      e = fac * fmaf(re, re, im * im);
    }
  }
  red[threadIdx.x] = e;
  __syncthreads();
  for (int s = 128; s > 0; s >>= 1) {
    if (threadIdx.x < s) red[threadIdx.x] += red[threadIdx.x + s];
    __syncthreads();
  }
  if (threadIdx.x == 0) bsum[blockIdx.x] = red[0];
}

__global__ void finalize(const float* __restrict__ bsum,
                         const float* __restrict__ box,
                         float* __restrict__ out)
{
  if (threadIdx.x == 0) {
    float acc = 0.f;
    for (int i = 0; i < S2_BLOCKS; ++i) acc += bsum[i];
    float C[3][3], det;
    cofactors(box, C, &det);
    // E = (2*pi/V)*full_sum = (4*pi/V)*half_sum
    out[0] = (4.0f * 3.14159265358979323846f / fabsf(det)) * acc;
  }
}

extern "C" void kernel_launch(void* const* d_in, const int* in_sizes, int n_in,
                              void* d_out, int out_size, void* d_ws, size_t ws_size,
                              hipStream_t stream) {
  const float* coords = (const float*)d_in[0];
  const float* box    = (const float*)d_in[1];
  const float* q      = (const float*)d_in[2];
  float* out = (float*)d_out;
  const int N = in_sizes[2];

  // ws: [0, NKV*64*8B = 4,006,400) float2 partials; [8 MiB, +124) block sums
  float* partial = (float*)d_ws;
  float* bsum    = (float*)((char*)d_ws + (8 << 20));

  const dim3 grid((NLINE + 3) / 4, NSLICE);   // 79 x 8 = 632 blocks, one pass
  hipLaunchKernelGGL(ewald_lines, grid, dim3(256), 0, stream,
                     coords, box, q, N, partial);
  hipLaunchKernelGGL(stage2, dim3(S2_BLOCKS), dim3(256), 0, stream,
                     partial, box, bsum);
  hipLaunchKernelGGL(finalize, dim3(1), dim3(64), 0, stream, bsum, box, out);
}

// Round 5
// 24.151 us; speedup vs baseline: 1.0551x; 1.0551x over previous
//
#include <hip/hip_runtime.h>
#include <math.h>

namespace {
constexpr int   KMAX   = 12;
constexpr int   NLINE  = 313;                    // half-space (h,k) lines
constexpr int   NGROUP = NLINE * 5;              // 1565 l-groups of 5
constexpr int   NKV    = NGROUP * 5;             // 7825 computed k-vecs (13 masked)
constexpr int   NSLICE = 4;                      // particle slices
constexpr int   SLICE_CAP = 512;                 // staged particles per chunk
constexpr int   S2_BLOCKS = (NKV + 255) / 256;   // 31
constexpr float ALPHA_  = 0.34f;
constexpr float TWO_PI_ = 6.283185307179586f;
}

__device__ __forceinline__ void cofactors(const float* __restrict__ box,
                                          float C[3][3], float* det) {
  const float b00 = box[0], b01 = box[1], b02 = box[2];
  const float b10 = box[3], b11 = box[4], b12 = box[5];
  const float b20 = box[6], b21 = box[7], b22 = box[8];
  C[0][0] =  (b11 * b22 - b12 * b21);
  C[0][1] = -(b10 * b22 - b12 * b20);
  C[0][2] =  (b10 * b21 - b11 * b20);
  C[1][0] = -(b01 * b22 - b02 * b21);
  C[1][1] =  (b00 * b22 - b02 * b20);
  C[1][2] = -(b00 * b21 - b01 * b20);
  C[2][0] =  (b01 * b12 - b02 * b11);
  C[2][1] = -(b00 * b12 - b02 * b10);
  C[2][2] =  (b00 * b11 - b01 * b10);
  *det = b00 * C[0][0] + b01 * C[0][1] + b02 * C[0][2];
}

// Half-space lines: L<300: h=1..12 x k=-12..12; L=300..311: h=0,k=1..12; L=312: h=k=0.
__device__ __forceinline__ void line_hk(int L, int* h, int* k) {
  if (L < 300)      { *h = L / 25 + 1; *k = L % 25 - 12; }
  else if (L < 312) { *h = 0;          *k = L - 299;     }
  else              { *h = 0;          *k = 0;           }
}

// One wave = one l-group (5 l of one (h,k) line) x one particle slice.
// Rotator sincos hoisted to staging: inner loop = 1 fract + 2 trans per particle.
__global__ __launch_bounds__(256, 6) void ewald_g5(
    const float* __restrict__ coords, const float* __restrict__ box,
    const float* __restrict__ q, int N, float2* __restrict__ partial)
{
  __shared__ float4 sf4[SLICE_CAP];   // (a, b, cr, sr)
  __shared__ float2 sf2[SLICE_CAP];   // (c, q)

  float C[3][3], det;
  cofactors(box, C, &det);
  const float invdet = 1.0f / det;

  const int slice = blockIdx.y;
  const int sp    = (N + NSLICE - 1) / NSLICE;
  const int s_beg = slice * sp;
  const int s_end = min(s_beg + sp, N);

  const int lane = threadIdx.x & 63;
  const int g    = blockIdx.x * 4 + (threadIdx.x >> 6);
  const int gc   = (g < NGROUP) ? g : (NGROUP - 1);  // clamp for decode; store guarded

  int h, k; line_hk(gc / 5, &h, &k);
  const float hf  = (float)h;
  const float kf  = (float)k;
  const float l0f = (float)(-KMAX + 5 * (gc % 5));

  float Sre[5] = {0.f, 0.f, 0.f, 0.f, 0.f};
  float Sim[5] = {0.f, 0.f, 0.f, 0.f, 0.f};

  for (int cb = s_beg; cb < s_end; cb += SLICE_CAP) {
    const int cnt = min(SLICE_CAP, s_end - cb);
    __syncthreads();
    for (int t = threadIdx.x; t < SLICE_CAP; t += 256) {
      float4 v4 = make_float4(0.f, 0.f, 1.f, 0.f);
      float2 v2 = make_float2(0.f, 0.f);
      if (t < cnt) {
        const int gi = cb + t;
        const float x = coords[3 * gi + 0];
        const float y = coords[3 * gi + 1];
        const float z = coords[3 * gi + 2];
        v4.x = (x * C[0][0] + y * C[0][1] + z * C[0][2]) * invdet;   // a
        v4.y = (x * C[1][0] + y * C[1][1] + z * C[1][2]) * invdet;   // b
        float c = (x * C[2][0] + y * C[2][1] + z * C[2][2]) * invdet;
        c = c - floorf(c);                                           // c in [0,1)
        float cr, sr;
        asm("v_sin_f32 %0, %1" : "=v"(sr) : "v"(c));                 // e^{2*pi*i*c}
        asm("v_cos_f32 %0, %1" : "=v"(cr) : "v"(c));
        v4.z = cr; v4.w = sr;
        v2.x = c;  v2.y = q[gi];
      }
      sf4[t] = v4; sf2[t] = v2;
    }
    __syncthreads();

#pragma unroll 2
    for (int i = lane; i < SLICE_CAP; i += 64) {
      const float4 p = sf4[i];
      const float2 w = sf2[i];
      float t0 = fmaf(hf, p.x, fmaf(kf, p.y, l0f * w.x));  // phase(l0), revolutions
      float tf;
      asm("v_fract_f32 %0, %1" : "=v"(tf) : "v"(t0));
      float s0, c0;
      asm("v_sin_f32 %0, %1" : "=v"(s0) : "v"(tf));
      asm("v_cos_f32 %0, %1" : "=v"(c0) : "v"(tf));
      float Pre = w.y * c0, Pim = w.y * s0;                // q folded into phasor
      Sre[0] += Pre; Sim[0] += Pim;
      const float cr = p.z, sr = p.w;
#pragma unroll
      for (int u = 1; u < 5; ++u) {
        const float nre = fmaf(Pre, cr, -(Pim * sr));
        const float nim = fmaf(Pre, sr,  (Pim * cr));
        Pre = nre; Pim = nim;
        Sre[u] += Pre; Sim[u] += Pim;
      }
    }
  }

#pragma unroll
  for (int off = 32; off > 0; off >>= 1) {
#pragma unroll
    for (int u = 0; u < 5; ++u) {
      Sre[u] += __shfl_xor(Sre[u], off);
      Sim[u] += __shfl_xor(Sim[u], off);
    }
  }

  if (g < NGROUP && lane == 0) {
#pragma unroll
    for (int u = 0; u < 5; ++u) {
      partial[(size_t)(g * 5 + u) * NSLICE + slice] = make_float2(Sre[u], Sim[u]);
    }
  }
}

// Sum slices, square, weight by fac, scale by 4*pi/V; one atomicAdd per block.
__global__ __launch_bounds__(256) void stage2(
    const float2* __restrict__ partial, const float* __restrict__ box,
    float* __restrict__ out)
{
  __shared__ float red[256];
  const int idx = blockIdx.x * 256 + threadIdx.x;   // kvec index = g*5+u
  float e = 0.f;
  if (idx < NKV) {
    const int g = idx / 5, u = idx % 5;
    const int line = g / 5;
    const int l = -KMAX + 5 * (g % 5) + u;
    int h, k; line_hk(line, &h, &k);
    if (!(h == 0 && k == 0 && l <= 0)) {   // mask the 13 non-half-space entries
      float re = 0.f, im = 0.f;
      for (int s = 0; s < NSLICE; ++s) {
        const float2 p = partial[(size_t)idx * NSLICE + s];
        re += p.x; im += p.y;
      }
      float C[3][3], det;
      cofactors(box, C, &det);
      const float invdet = 1.0f / det;
      const float hf = (float)h, kf = (float)k, lf = (float)l;
      const float kx = (hf * C[0][0] + kf * C[1][0] + lf * C[2][0]) * invdet;
      const float ky = (hf * C[0][1] + kf * C[1][1] + lf * C[2][1]) * invdet;
      const float kz = (hf * C[0][2] + kf * C[1][2] + lf * C[2][2]) * invdet;
      const float k2 = TWO_PI_ * TWO_PI_ * (kx * kx + ky * ky + kz * kz);
      const float fac = __expf(-k2 / (4.0f * ALPHA_ * ALPHA_)) / k2;
      e = fac * fmaf(re, re, im * im);
    }
  }
  red[threadIdx.x] = e;
  __syncthreads();
  for (int s = 128; s > 0; s >>= 1) {
    if (threadIdx.x < s) red[threadIdx.x] += red[threadIdx.x + s];
    __syncthreads();
  }
  if (threadIdx.x == 0) {
    float C[3][3], det;
    cofactors(box, C, &det);
    // E = (2*pi/V)*full_sum = (4*pi/V)*half_sum
    const float scale = (4.0f * 3.14159265358979323846f) / fabsf(det);
    atomicAdd(out, scale * red[0]);
  }
}

extern "C" void kernel_launch(void* const* d_in, const int* in_sizes, int n_in,
                              void* d_out, int out_size, void* d_ws, size_t ws_size,
                              hipStream_t stream) {
  const float* coords = (const float*)d_in[0];
  const float* box    = (const float*)d_in[1];
  const float* q      = (const float*)d_in[2];
  float* out = (float*)d_out;
  const int N = in_sizes[2];

  // ws: [0, NKV*NSLICE*8B = 250,400 B) float2 partial structure factors
  float2* partial = (float2*)d_ws;

  hipMemsetAsync(out, 0, sizeof(float), stream);   // atomic target; graph-capturable
  const dim3 grid((NGROUP + 3) / 4, NSLICE);       // 392 x 4 = 1568 blocks, one pass
  hipLaunchKernelGGL(ewald_g5, grid, dim3(256), 0, stream,
                     coords, box, q, N, partial);
  hipLaunchKernelGGL(stage2, dim3(S2_BLOCKS), dim3(256), 0, stream,
                     partial, box, out);
}

// Round 6
// 20.080 us; speedup vs baseline: 1.2690x; 1.2028x over previous
//
#include <hip/hip_runtime.h>
#include <math.h>

namespace {
constexpr int   KMAX   = 12;
constexpr int   NLINE  = 313;                    // half-space (h,k) lines
constexpr int   NGROUP = NLINE * 5;              // 1565 l-groups of 5
constexpr int   NKV    = NGROUP * 5;             // 7825 computed k-vecs (13 masked)
constexpr int   NSLICE = 8;                      // particle slices
constexpr int   SLICE_CAP = 512;                 // staged particles per chunk
constexpr int   S2_BLOCKS = (NKV + 255) / 256;   // 31
constexpr float ALPHA_  = 0.34f;
constexpr float TWO_PI_ = 6.283185307179586f;
}

__device__ __forceinline__ void cofactors(const float* __restrict__ box,
                                          float C[3][3], float* det) {
  const float b00 = box[0], b01 = box[1], b02 = box[2];
  const float b10 = box[3], b11 = box[4], b12 = box[5];
  const float b20 = box[6], b21 = box[7], b22 = box[8];
  C[0][0] =  (b11 * b22 - b12 * b21);
  C[0][1] = -(b10 * b22 - b12 * b20);
  C[0][2] =  (b10 * b21 - b11 * b20);
  C[1][0] = -(b01 * b22 - b02 * b21);
  C[1][1] =  (b00 * b22 - b02 * b20);
  C[1][2] = -(b00 * b21 - b01 * b20);
  C[2][0] =  (b01 * b12 - b02 * b11);
  C[2][1] = -(b00 * b12 - b02 * b10);
  C[2][2] =  (b00 * b11 - b01 * b10);
  *det = b00 * C[0][0] + b01 * C[0][1] + b02 * C[0][2];
}

// Half-space lines: L<300: h=1..12 x k=-12..12; L=300..311: h=0,k=1..12; L=312: h=k=0.
__device__ __forceinline__ void line_hk(int L, int* h, int* k) {
  if (L < 300)      { *h = L / 25 + 1; *k = L % 25 - 12; }
  else if (L < 312) { *h = 0;          *k = L - 299;     }
  else              { *h = 0;          *k = 0;           }
}

// One wave = one l-group (5 consecutive l of one (h,k) line) x one particle slice.
// (Identical to the proven R3 kernel; only addition: one thread zeroes out[0].)
__global__ __launch_bounds__(256) void ewald_groups(
    const float* __restrict__ coords, const float* __restrict__ box,
    const float* __restrict__ q, int N, float* __restrict__ partial,
    float* __restrict__ out)
{
  __shared__ float4 sf[SLICE_CAP];

  // Zero the atomic target for stage2 (stream-ordered: stage2 runs after us).
  if (blockIdx.x == 0 && blockIdx.y == 0 && threadIdx.x == 0) out[0] = 0.0f;

  float C[3][3], det;
  cofactors(box, C, &det);
  const float invdet = 1.0f / det;

  const int slice = blockIdx.y;
  const int sp    = (N + NSLICE - 1) / NSLICE;
  const int s_beg = slice * sp;
  const int s_end = min(s_beg + sp, N);

  const int lane = threadIdx.x & 63;
  const int g    = blockIdx.x * 4 + (threadIdx.x >> 6);
  const int gc   = (g < NGROUP) ? g : (NGROUP - 1);   // clamp for decode; store guarded

  int h, k; line_hk(gc / 5, &h, &k);
  const float hf  = (float)h;
  const float kf  = (float)k;
  const float l0f = (float)(-KMAX + 5 * (gc % 5));

  float Sre[5] = {0.f, 0.f, 0.f, 0.f, 0.f};
  float Sim[5] = {0.f, 0.f, 0.f, 0.f, 0.f};

  for (int cb = s_beg; cb < s_end; cb += SLICE_CAP) {
    const int cnt = min(SLICE_CAP, s_end - cb);
    __syncthreads();
    // Stage fractional coords + charge for this chunk (pad with q=0).
    for (int t = threadIdx.x; t < SLICE_CAP; t += 256) {
      float4 v = make_float4(0.f, 0.f, 0.f, 0.f);
      if (t < cnt) {
        const int gi = cb + t;
        const float x = coords[3 * gi + 0];
        const float y = coords[3 * gi + 1];
        const float z = coords[3 * gi + 2];
        v.x = (x * C[0][0] + y * C[0][1] + z * C[0][2]) * invdet;  // a
        v.y = (x * C[1][0] + y * C[1][1] + z * C[1][2]) * invdet;  // b
        float c = (x * C[2][0] + y * C[2][1] + z * C[2][2]) * invdet;
        v.z = c - floorf(c);                                       // c in [0,1)
        v.w = q[gi];
      }
      sf[t] = v;
    }
    __syncthreads();

    for (int i = lane; i < SLICE_CAP; i += 64) {
      const float4 p = sf[i];
      float t = fmaf(hf, p.x, fmaf(kf, p.y, l0f * p.z));  // phase(l0) in revolutions
      float tf;
      asm("v_fract_f32 %0, %1" : "=v"(tf) : "v"(t));
      float s0, c0, sr, cr;
      asm("v_sin_f32 %0, %1" : "=v"(s0) : "v"(tf));
      asm("v_cos_f32 %0, %1" : "=v"(c0) : "v"(tf));
      asm("v_sin_f32 %0, %1" : "=v"(sr) : "v"(p.z));      // rotator e^{i*2pi*c}
      asm("v_cos_f32 %0, %1" : "=v"(cr) : "v"(p.z));
      float Pre = p.w * c0, Pim = p.w * s0;               // q folded into phasor
      Sre[0] += Pre; Sim[0] += Pim;
#pragma unroll
      for (int u = 1; u < 5; ++u) {
        const float nre = fmaf(Pre, cr, -(Pim * sr));
        const float nim = fmaf(Pre, sr,  (Pim * cr));
        Pre = nre; Pim = nim;
        Sre[u] += Pre; Sim[u] += Pim;
      }
    }
  }

#pragma unroll
  for (int off = 32; off > 0; off >>= 1) {
#pragma unroll
    for (int u = 0; u < 5; ++u) {
      Sre[u] += __shfl_down(Sre[u], off);
      Sim[u] += __shfl_down(Sim[u], off);
    }
  }
  if (g < NGROUP && lane == 0) {
    float* dst = partial + (size_t)(g * NSLICE + slice) * 10;
#pragma unroll
    for (int u = 0; u < 5; ++u) {
      dst[2 * u + 0] = Sre[u];
      dst[2 * u + 1] = Sim[u];
    }
  }
}

// Sum slices, square, weight by fac, scale by 4*pi/V; one atomicAdd per block.
__global__ __launch_bounds__(256) void stage2(
    const float* __restrict__ partial, const float* __restrict__ box,
    float* __restrict__ out)
{
  __shared__ float red[256];
  const int idx = blockIdx.x * 256 + threadIdx.x;
  float e = 0.f;
  if (idx < NKV) {
    const int g = idx / 5, u = idx % 5;
    const int L = g / 5, sub = g % 5;
    int h, k; line_hk(L, &h, &k);
    const int l = -KMAX + 5 * sub + u;
    if (!(h == 0 && k == 0 && l <= 0)) {   // mask the 13 non-half-space entries
      float re = 0.f, im = 0.f;
      for (int s = 0; s < NSLICE; ++s) {
        const float* p = partial + (size_t)(g * NSLICE + s) * 10 + 2 * u;
        re += p[0]; im += p[1];
      }
      float C[3][3], det;
      cofactors(box, C, &det);
      const float invdet = 1.0f / det;
      const float hf = (float)h, kf = (float)k, lf = (float)l;
      const float kx = (hf * C[0][0] + kf * C[1][0] + lf * C[2][0]) * invdet;
      const float ky = (hf * C[0][1] + kf * C[1][1] + lf * C[2][1]) * invdet;
      const float kz = (hf * C[0][2] + kf * C[1][2] + lf * C[2][2]) * invdet;
      const float k2 = TWO_PI_ * TWO_PI_ * (kx * kx + ky * ky + kz * kz);
      const float fac = __expf(-k2 / (4.0f * ALPHA_ * ALPHA_)) / k2;
      e = fac * fmaf(re, re, im * im);
    }
  }
  red[threadIdx.x] = e;
  __syncthreads();
  for (int s = 128; s > 0; s >>= 1) {
    if (threadIdx.x < s) red[threadIdx.x] += red[threadIdx.x + s];
    __syncthreads();
  }
  if (threadIdx.x == 0) {
    float C[3][3], det;
    cofactors(box, C, &det);
    // E = (2*pi/V)*full_sum = (4*pi/V)*half_sum
    const float scale = (4.0f * 3.14159265358979323846f) / fabsf(det);
    atomicAdd(out, scale * red[0]);
  }
}

extern "C" void kernel_launch(void* const* d_in, const int* in_sizes, int n_in,
                              void* d_out, int out_size, void* d_ws, size_t ws_size,
                              hipStream_t stream) {
  const float* coords = (const float*)d_in[0];
  const float* box    = (const float*)d_in[1];
  const float* q      = (const float*)d_in[2];
  float* out = (float*)d_out;
  const int N = in_sizes[2];

  // ws: [0, NGROUP*NSLICE*10*4 = 500,800 B) partial structure factors
  float* partial = (float*)d_ws;

  const dim3 grid((NGROUP + 3) / 4, NSLICE);   // 392 x 8 = 3136 blocks
  hipLaunchKernelGGL(ewald_groups, grid, dim3(256), 0, stream,
                     coords, box, q, N, partial, out);
  hipLaunchKernelGGL(stage2, dim3(S2_BLOCKS), dim3(256), 0, stream,
                     partial, box, out);
}